// Round 1
// baseline (18135.060 us; speedup 1.0000x reference)
//
#include <hip/hip_runtime.h>
#include <math.h>

// Problem constants (from reference): N=32768 X-matrices, C=128 classes, n=64.
#define N_X 32768
#define N_P 128
#define ND 64
#define MAT (ND*ND)          // 4096
#define MAX_SWEEP 15
// converged when max over pairs of cross^2/(dpp*dqq) <= TOL2  (ratio 1e-4)
#define TOL2 1e-8f

// ---------------------------------------------------------------------------
// Kernel 1: symmetrize A in place: upper <- mirror of strict lower (tril conv).
// Writers touch only (r,col) with col>r; readers read only (col,r) with col>r
// (i.e. strictly-lower elements, never written) -> no race.
// ---------------------------------------------------------------------------
__global__ __launch_bounds__(256) void symmetrize_kernel(float* __restrict__ A) {
    const int idx = blockIdx.x * 256 + threadIdx.x;   // 128*4096 total
    const int r   = (idx >> 6) & 63;
    const int col = idx & 63;
    if (col > r) A[idx] = A[(idx & ~4095) | (col << 6) | r];
}

// ---------------------------------------------------------------------------
// Kernel 2: batched SPD logm via one-sided Jacobi. One wave (64 lanes) per
// matrix; lane k holds column k in registers. XOR-pair rounds m=1..63.
// Writes logm over the input matrix in place.
// ---------------------------------------------------------------------------
__global__ __launch_bounds__(64, 2) void jacobi_logm_kernel(float* __restrict__ X,
                                                            float* __restrict__ P) {
    const int b = blockIdx.x;
    float* M = (b < N_X) ? (X + (size_t)b * MAT)
                         : (P + (size_t)(b - N_X) * MAT);
    const int lane = threadIdx.x;

    // load column `lane` (coalesced across lanes per i)
    float w[ND];
    #pragma unroll
    for (int i = 0; i < ND; ++i) w[i] = M[i * ND + lane];

    // own = ||w||^2, maintained incrementally across rounds
    float own = 0.f;
    #pragma unroll
    for (int i = 0; i < ND; ++i) own = fmaf(w[i], w[i], own);

    #pragma unroll 1
    for (int s = 0; s < MAX_SWEEP; ++s) {
        float maxviol = 0.f;
        #pragma unroll 1
        for (int m = 1; m < ND; ++m) {
            float pw[ND];
            float cross = 0.f;
            #pragma unroll
            for (int i = 0; i < ND; ++i) {
                pw[i] = __shfl_xor(w[i], m);
                cross = fmaf(w[i], pw[i], cross);
            }
            const float pown = __shfl_xor(own, m);
            const bool  isp  = lane < (lane ^ m);       // am I the lower index?
            const float dpp  = isp ? own  : pown;
            const float dqq  = isp ? pown : own;

            // convergence monitor: cross^2 - TOL2*dpp*dqq
            maxviol = fmaxf(maxviol, fmaf(cross, cross, -(TOL2 * own) * pown));

            // annihilating Jacobi rotation on 2x2 Gram [[dpp,dpq],[dpq,dqq]]
            const float tau = (dqq - dpp) / (2.f * cross);            // may be inf/nan
            const float t0  = copysignf(1.f, tau) /
                              (fabsf(tau) + sqrtf(fmaf(tau, tau, 1.f)));
            const float c0  = 1.f / sqrtf(fmaf(t0, t0, 1.f));
            const bool  ok  = fabsf(cross) > 1e-30f;                  // gate inf/nan path
            const float cc  = ok ? c0 : 1.f;
            const float tq  = ok ? t0 : 0.f;
            const float ss  = isp ? -(tq * cc) : (tq * cc);

            // p: w' = c*w - s*pw ; q: w' = s*pw + c*w
            #pragma unroll
            for (int i = 0; i < ND; ++i) w[i] = fmaf(cc, w[i], ss * pw[i]);

            // exact norm update: dpp' = dpp - t*dpq ; dqq' = dqq + t*dpq
            own = fmaf(isp ? -tq : tq, cross, own);
        }
        // wave-wide max -> uniform early exit for this matrix
        #pragma unroll
        for (int mm = 32; mm >= 1; mm >>= 1)
            maxviol = fmaxf(maxviol, __shfl_xor(maxviol, mm));
        if (maxviol <= 0.f) break;
    }

    // exact final norm^2 and log-coefficient:  logm = sum_k coef_k * w_k w_k^T
    float d = 0.f;
    #pragma unroll
    for (int i = 0; i < ND; ++i) d = fmaf(w[i], w[i], d);
    d = fmaxf(d, 1e-30f);
    const float coef = 0.5f * logf(d) / d;

    // recompose via LDS:  WT[k][i] = W[i][k]  (row k = column k, contiguous)
    __shared__ __align__(16) float WT[ND][68];   // 68: 16B-aligned rows, conflict-light
    __shared__ float Cf[ND];
    #pragma unroll
    for (int i4 = 0; i4 < 16; ++i4) {
        *(float4*)(&WT[lane][4 * i4]) =
            make_float4(w[4*i4], w[4*i4+1], w[4*i4+2], w[4*i4+3]);
    }
    Cf[lane] = coef;
    __syncthreads();

    float acc[ND];
    #pragma unroll
    for (int i = 0; i < ND; ++i) acc[i] = 0.f;

    // acc[i] = logm[i][lane] = sum_k (coef_k * W[lane][k]) * W[i][k]
    #pragma unroll 4
    for (int k = 0; k < ND; ++k) {
        const float sk = Cf[k] * WT[k][lane];          // conflict-free row read
        #pragma unroll
        for (int i4 = 0; i4 < 16; ++i4) {
            const float4 v = *(const float4*)(&WT[k][4 * i4]);  // broadcast
            acc[4*i4+0] = fmaf(sk, v.x, acc[4*i4+0]);
            acc[4*i4+1] = fmaf(sk, v.y, acc[4*i4+1]);
            acc[4*i4+2] = fmaf(sk, v.z, acc[4*i4+2]);
            acc[4*i4+3] = fmaf(sk, v.w, acc[4*i4+3]);
        }
    }

    // store logm in place (symmetric; coalesced across lanes per i)
    #pragma unroll
    for (int i = 0; i < ND; ++i) M[i * ND + lane] = acc[i];
}

// ---------------------------------------------------------------------------
// Kernel 3: off[c] = <logm(P_c), Asym_c>   (one wave per class)
// ---------------------------------------------------------------------------
__global__ __launch_bounds__(64) void off_kernel(const float* __restrict__ LP,
                                                 const float* __restrict__ AS,
                                                 float* __restrict__ off) {
    const int c = blockIdx.x, lane = threadIdx.x;
    const float* lp = LP + (size_t)c * MAT;
    const float* as = AS + (size_t)c * MAT;
    float t = 0.f;
    #pragma unroll 8
    for (int i = 0; i < ND; ++i)
        t = fmaf(lp[i * ND + lane], as[i * ND + lane], t);
    #pragma unroll
    for (int m = 32; m >= 1; m >>= 1) t += __shfl_xor(t, m);
    if (lane == 0) off[c] = t;
}

// ---------------------------------------------------------------------------
// Kernel 4: logits GEMM  out[n,c] = sum_k LX[n,k]*AS[c,k] - off[c]
// 128n x 128c tile per block, BK=32, 256 threads, 8x8 accs/thread.
// ---------------------------------------------------------------------------
__global__ __launch_bounds__(256) void logits_kernel(const float* __restrict__ LX,
                                                     const float* __restrict__ AS,
                                                     const float* __restrict__ off,
                                                     float* __restrict__ out) {
    __shared__ __align__(16) float LXs[32][132];
    __shared__ __align__(16) float ASs[32][132];
    const int tid = threadIdx.x;
    const int tx = tid & 15, ty = tid >> 4;
    const int nbase = blockIdx.x * 128;

    float offv[8];
    #pragma unroll
    for (int j = 0; j < 8; ++j) offv[j] = off[tx * 8 + j];

    float acc[8][8];
    #pragma unroll
    for (int i = 0; i < 8; ++i)
        #pragma unroll
        for (int j = 0; j < 8; ++j) acc[i][j] = 0.f;

    #pragma unroll 1
    for (int kc = 0; kc < MAT; kc += 32) {
        #pragma unroll
        for (int u = 0; u < 4; ++u) {
            const int f  = u * 256 + tid;      // 1024 float4 per buffer
            const int r  = f >> 3;             // row 0..127
            const int c4 = (f & 7) * 4;        // k sub-offset
            const float4 v = *(const float4*)(&LX[(size_t)(nbase + r) * MAT + kc + c4]);
            LXs[c4+0][r] = v.x; LXs[c4+1][r] = v.y; LXs[c4+2][r] = v.z; LXs[c4+3][r] = v.w;
            const float4 g = *(const float4*)(&AS[(size_t)r * MAT + kc + c4]);
            ASs[c4+0][r] = g.x; ASs[c4+1][r] = g.y; ASs[c4+2][r] = g.z; ASs[c4+3][r] = g.w;
        }
        __syncthreads();
        #pragma unroll 4
        for (int kk = 0; kk < 32; ++kk) {
            const float4 a0 = *(const float4*)(&LXs[kk][ty * 8]);
            const float4 a1 = *(const float4*)(&LXs[kk][ty * 8 + 4]);
            const float4 b0 = *(const float4*)(&ASs[kk][tx * 8]);
            const float4 b1 = *(const float4*)(&ASs[kk][tx * 8 + 4]);
            const float av[8] = {a0.x,a0.y,a0.z,a0.w,a1.x,a1.y,a1.z,a1.w};
            const float bv[8] = {b0.x,b0.y,b0.z,b0.w,b1.x,b1.y,b1.z,b1.w};
            #pragma unroll
            for (int i = 0; i < 8; ++i)
                #pragma unroll
                for (int j = 0; j < 8; ++j)
                    acc[i][j] = fmaf(av[i], bv[j], acc[i][j]);
        }
        __syncthreads();
    }

    #pragma unroll
    for (int i = 0; i < 8; ++i) {
        const int n = nbase + ty * 8 + i;
        const float4 o0 = make_float4(acc[i][0]-offv[0], acc[i][1]-offv[1],
                                      acc[i][2]-offv[2], acc[i][3]-offv[3]);
        const float4 o1 = make_float4(acc[i][4]-offv[4], acc[i][5]-offv[5],
                                      acc[i][6]-offv[6], acc[i][7]-offv[7]);
        *(float4*)(&out[(size_t)n * 128 + tx * 8])     = o0;
        *(float4*)(&out[(size_t)n * 128 + tx * 8 + 4]) = o1;
    }
}

// ---------------------------------------------------------------------------
extern "C" void kernel_launch(void* const* d_in, const int* in_sizes, int n_in,
                              void* d_out, int out_size, void* d_ws, size_t ws_size,
                              hipStream_t stream) {
    // inputs: X (32768*4096 f32), P (128*4096 f32), A (128*4096 f32)
    float* X = (float*)d_in[0];
    float* P = (float*)d_in[1];
    float* A = (float*)d_in[2];
    float* out = (float*)d_out;
    float* off = (float*)d_ws;            // 128 floats of scratch

    // 1) A <- sym(A) in place
    hipLaunchKernelGGL(symmetrize_kernel, dim3((N_P * MAT) / 256), dim3(256), 0, stream, A);
    // 2) X <- logm(X), P <- logm(P) in place (harness restores inputs each launch)
    hipLaunchKernelGGL(jacobi_logm_kernel, dim3(N_X + N_P), dim3(64), 0, stream, X, P);
    // 3) off[c] = <logm P_c, Asym_c>
    hipLaunchKernelGGL(off_kernel, dim3(N_P), dim3(64), 0, stream, P, A, off);
    // 4) logits
    hipLaunchKernelGGL(logits_kernel, dim3(N_X / 128), dim3(256), 0, stream, X, A, off, out);
}

// Round 3
// 17084.744 us; speedup vs baseline: 1.0615x; 1.0615x over previous
//
#include <hip/hip_runtime.h>
#include <math.h>

// Problem constants: N=32768 X-matrices, C=128 classes, n=64.
#define N_X 32768
#define N_P 128
#define ND 64
#define MAT (ND*ND)          // 4096
#define MAX_SWEEP 15
// converged when max over pairs of cross^2/(dpp*dqq) <= TOL2 (ratio ~3e-4)
#define TOL2 1e-7f

typedef float v2f __attribute__((ext_vector_type(2)));

__device__ __forceinline__ float bperm_f(int addr, float v) {
    return __builtin_bit_cast(float,
        __builtin_amdgcn_ds_bpermute(addr, __builtin_bit_cast(int, v)));
}

#if __has_builtin(__builtin_elementwise_fma)
__device__ __forceinline__ v2f vfma(v2f a, v2f b, v2f c) {
    return __builtin_elementwise_fma(a, b, c);
}
#else
__device__ __forceinline__ v2f vfma(v2f a, v2f b, v2f c) {
    return v2f{fmaf(a.x, b.x, c.x), fmaf(a.y, b.y, c.y)};
}
#endif

// ---------------------------------------------------------------------------
// Kernel 1: symmetrize A in place (tril + tril^T + diag).
// ---------------------------------------------------------------------------
__global__ __launch_bounds__(256) void symmetrize_kernel(float* __restrict__ A) {
    const int idx = blockIdx.x * 256 + threadIdx.x;   // 128*4096 total
    const int r   = (idx >> 6) & 63;
    const int col = idx & 63;
    if (col > r) A[idx] = A[(idx & ~4095) | (col << 6) | r];
}

// ---------------------------------------------------------------------------
// Kernel 2: one-sided Jacobi. One wave per matrix, 4 matrices per 256-thread
// block, NO LDS (occupancy VGPR-bound). Lane k holds column k as v2f[32].
// Leaves converged columns W in place over the input and coef_k in `coefs`.
// ---------------------------------------------------------------------------
__global__ __launch_bounds__(256, 3) void jacobi_kernel(float* __restrict__ X,
                                                        float* __restrict__ P,
                                                        float* __restrict__ coefs) {
    const int lane = threadIdx.x & 63;
    const int b    = blockIdx.x * 4 + (threadIdx.x >> 6);
    float* M = (b < N_X) ? (X + (size_t)b * MAT)
                         : (P + (size_t)(b - N_X) * MAT);
    const int lane4 = lane << 2;

    v2f w[32];
    #pragma unroll
    for (int i = 0; i < 32; ++i)
        w[i] = v2f{ M[(2*i) * ND + lane], M[(2*i+1) * ND + lane] };

    v2f o2 = {0.f, 0.f};
    #pragma unroll
    for (int i = 0; i < 32; ++i) o2 = vfma(w[i], w[i], o2);
    float own = o2.x + o2.y;

    #pragma unroll 1
    for (int s = 0; s < MAX_SWEEP; ++s) {
        float maxviol = 0.f;
        #pragma unroll 1
        for (int m = 1; m < ND; ++m) {
            const int pa = lane4 ^ (m << 2);
            v2f pw[32];
            v2f c0 = {0.f,0.f}, c1 = {0.f,0.f}, c2 = {0.f,0.f}, c3 = {0.f,0.f};
            #pragma unroll
            for (int i = 0; i < 32; i += 4) {
                pw[i+0] = v2f{ bperm_f(pa, w[i+0].x), bperm_f(pa, w[i+0].y) };
                pw[i+1] = v2f{ bperm_f(pa, w[i+1].x), bperm_f(pa, w[i+1].y) };
                pw[i+2] = v2f{ bperm_f(pa, w[i+2].x), bperm_f(pa, w[i+2].y) };
                pw[i+3] = v2f{ bperm_f(pa, w[i+3].x), bperm_f(pa, w[i+3].y) };
                c0 = vfma(w[i+0], pw[i+0], c0);
                c1 = vfma(w[i+1], pw[i+1], c1);
                c2 = vfma(w[i+2], pw[i+2], c2);
                c3 = vfma(w[i+3], pw[i+3], c3);
            }
            const v2f  cs    = (c0 + c1) + (c2 + c3);
            const float cross = cs.x + cs.y;
            const float pown  = bperm_f(pa, own);
            const bool  isp   = lane < (lane ^ m);
            const float dpp   = isp ? own  : pown;
            const float dqq   = isp ? pown : own;

            // convergence monitor BEFORE updating own
            maxviol = fmaxf(maxviol, fmaf(cross, cross, -(TOL2 * own) * pown));

            // annihilating rotation on 2x2 Gram [[dpp,dpq],[dpq,dqq]]
            const float tau = (dqq - dpp) / (2.f * cross);
            const float t0  = copysignf(1.f, tau) /
                              (fabsf(tau) + sqrtf(fmaf(tau, tau, 1.f)));
            const float c0r = 1.f / sqrtf(fmaf(t0, t0, 1.f));
            const bool  ok  = fabsf(cross) > 1e-30f;
            const float cc  = ok ? c0r : 1.f;
            const float tq  = ok ? t0  : 0.f;
            const float ss  = isp ? -(tq * cc) : (tq * cc);

            const v2f ccv = {cc, cc}, ssv = {ss, ss};
            #pragma unroll
            for (int i = 0; i < 32; ++i)
                w[i] = vfma(ccv, w[i], pw[i] * ssv);

            own = fmaf(isp ? -tq : tq, cross, own);
        }
        // wave-wide max -> uniform early exit
        #pragma unroll
        for (int mm = 32; mm >= 1; mm >>= 1)
            maxviol = fmaxf(maxviol, bperm_f(lane4 ^ (mm << 2), maxviol));
        if (maxviol <= 0.f) break;
    }

    // exact final norm^2, coef_k = 0.5*log(d)/d
    v2f d2 = {0.f, 0.f};
    #pragma unroll
    for (int i = 0; i < 32; ++i) d2 = vfma(w[i], w[i], d2);
    const float d = fmaxf(d2.x + d2.y, 1e-30f);
    coefs[(size_t)b * ND + lane] = 0.5f * logf(d) / d;

    #pragma unroll
    for (int i = 0; i < 32; ++i) {
        M[(2*i) * ND + lane]   = w[i].x;
        M[(2*i+1) * ND + lane] = w[i].y;
    }
}

// ---------------------------------------------------------------------------
// Kernel 3: recompose logm[i][j] = sum_k coef_k * W[i][k] * W[j][k].
// One matrix per 256-thread block, in place over W.
// NOTE: the B-operand is scaled by the wave-uniform Cf[k] (contraction index),
// NOT by a per-column coef — that was R2's bug.
// ---------------------------------------------------------------------------
__global__ __launch_bounds__(256, 4) void recompose_kernel(float* __restrict__ X,
                                                           float* __restrict__ P,
                                                           const float* __restrict__ coefs) {
    __shared__ __align__(16) float WR[ND][68];   // WR[k][i] = W[i][k]
    __shared__ float Cf[ND];
    const int b = blockIdx.x;
    float* M = (b < N_X) ? (X + (size_t)b * MAT)
                         : (P + (size_t)(b - N_X) * MAT);
    const int tid = threadIdx.x;

    { // load + transpose: thread -> row r, 16-col segment q
        const int r = tid >> 2, q = (tid & 3) * 16;
        const float4 v0 = *(const float4*)(&M[r * ND + q + 0]);
        const float4 v1 = *(const float4*)(&M[r * ND + q + 4]);
        const float4 v2 = *(const float4*)(&M[r * ND + q + 8]);
        const float4 v3 = *(const float4*)(&M[r * ND + q + 12]);
        WR[q+ 0][r]=v0.x; WR[q+ 1][r]=v0.y; WR[q+ 2][r]=v0.z; WR[q+ 3][r]=v0.w;
        WR[q+ 4][r]=v1.x; WR[q+ 5][r]=v1.y; WR[q+ 6][r]=v1.z; WR[q+ 7][r]=v1.w;
        WR[q+ 8][r]=v2.x; WR[q+ 9][r]=v2.y; WR[q+10][r]=v2.z; WR[q+11][r]=v2.w;
        WR[q+12][r]=v3.x; WR[q+13][r]=v3.y; WR[q+14][r]=v3.z; WR[q+15][r]=v3.w;
    }
    if (tid < ND) Cf[tid] = coefs[(size_t)b * ND + tid];
    __syncthreads();

    const int tx = tid & 15, ty = tid >> 4;   // 4x4 output block per thread

    v2f a00={0,0},a01={0,0},a10={0,0},a11={0,0},
        a20={0,0},a21={0,0},a30={0,0},a31={0,0};

    #pragma unroll 4
    for (int k = 0; k < ND; ++k) {
        const v2f* row = (const v2f*)(&WR[k][0]);
        const float sk = Cf[k];                              // coef of contraction idx
        const v2f skv = {sk, sk};
        const v2f aA = row[ty*2], aB = row[ty*2 + 1];        // broadcast reads
        const v2f b0 = row[tx*2] * skv, b1 = row[tx*2 + 1] * skv;
        const v2f ax0 = {aA.x, aA.x}, ax1 = {aA.y, aA.y};
        const v2f ax2 = {aB.x, aB.x}, ax3 = {aB.y, aB.y};
        a00 = vfma(ax0, b0, a00);  a01 = vfma(ax0, b1, a01);
        a10 = vfma(ax1, b0, a10);  a11 = vfma(ax1, b1, a11);
        a20 = vfma(ax2, b0, a20);  a21 = vfma(ax2, b1, a21);
        a30 = vfma(ax3, b0, a30);  a31 = vfma(ax3, b1, a31);
    }

    const int i0 = ty * 4, j0 = tx * 4;
    *(float4*)(&M[(size_t)(i0+0)*ND + j0]) = make_float4(a00.x,a00.y,a01.x,a01.y);
    *(float4*)(&M[(size_t)(i0+1)*ND + j0]) = make_float4(a10.x,a10.y,a11.x,a11.y);
    *(float4*)(&M[(size_t)(i0+2)*ND + j0]) = make_float4(a20.x,a20.y,a21.x,a21.y);
    *(float4*)(&M[(size_t)(i0+3)*ND + j0]) = make_float4(a30.x,a30.y,a31.x,a31.y);
}

// ---------------------------------------------------------------------------
// Kernel 4: off[c] = <logm(P_c), Asym_c>   (one wave per class)
// ---------------------------------------------------------------------------
__global__ __launch_bounds__(64) void off_kernel(const float* __restrict__ LP,
                                                 const float* __restrict__ AS,
                                                 float* __restrict__ off) {
    const int c = blockIdx.x, lane = threadIdx.x;
    const float* lp = LP + (size_t)c * MAT;
    const float* as = AS + (size_t)c * MAT;
    float t = 0.f;
    #pragma unroll 8
    for (int i = 0; i < ND; ++i)
        t = fmaf(lp[i * ND + lane], as[i * ND + lane], t);
    #pragma unroll
    for (int m = 32; m >= 1; m >>= 1) t += __shfl_xor(t, m);
    if (lane == 0) off[c] = t;
}

// ---------------------------------------------------------------------------
// Kernel 5: logits GEMM  out[n,c] = sum_k LX[n,k]*AS[c,k] - off[c]
// ---------------------------------------------------------------------------
__global__ __launch_bounds__(256) void logits_kernel(const float* __restrict__ LX,
                                                     const float* __restrict__ AS,
                                                     const float* __restrict__ off,
                                                     float* __restrict__ out) {
    __shared__ __align__(16) float LXs[32][132];
    __shared__ __align__(16) float ASs[32][132];
    const int tid = threadIdx.x;
    const int tx = tid & 15, ty = tid >> 4;
    const int nbase = blockIdx.x * 128;

    float offv[8];
    #pragma unroll
    for (int j = 0; j < 8; ++j) offv[j] = off[tx * 8 + j];

    float acc[8][8];
    #pragma unroll
    for (int i = 0; i < 8; ++i)
        #pragma unroll
        for (int j = 0; j < 8; ++j) acc[i][j] = 0.f;

    #pragma unroll 1
    for (int kc = 0; kc < MAT; kc += 32) {
        #pragma unroll
        for (int u = 0; u < 4; ++u) {
            const int f  = u * 256 + tid;
            const int r  = f >> 3;
            const int c4 = (f & 7) * 4;
            const float4 v = *(const float4*)(&LX[(size_t)(nbase + r) * MAT + kc + c4]);
            LXs[c4+0][r] = v.x; LXs[c4+1][r] = v.y; LXs[c4+2][r] = v.z; LXs[c4+3][r] = v.w;
            const float4 g = *(const float4*)(&AS[(size_t)r * MAT + kc + c4]);
            ASs[c4+0][r] = g.x; ASs[c4+1][r] = g.y; ASs[c4+2][r] = g.z; ASs[c4+3][r] = g.w;
        }
        __syncthreads();
        #pragma unroll 4
        for (int kk = 0; kk < 32; ++kk) {
            const float4 a0 = *(const float4*)(&LXs[kk][ty * 8]);
            const float4 a1 = *(const float4*)(&LXs[kk][ty * 8 + 4]);
            const float4 b0 = *(const float4*)(&ASs[kk][tx * 8]);
            const float4 b1 = *(const float4*)(&ASs[kk][tx * 8 + 4]);
            const float av[8] = {a0.x,a0.y,a0.z,a0.w,a1.x,a1.y,a1.z,a1.w};
            const float bv[8] = {b0.x,b0.y,b0.z,b0.w,b1.x,b1.y,b1.z,b1.w};
            #pragma unroll
            for (int i = 0; i < 8; ++i)
                #pragma unroll
                for (int j = 0; j < 8; ++j)
                    acc[i][j] = fmaf(av[i], bv[j], acc[i][j]);
        }
        __syncthreads();
    }

    #pragma unroll
    for (int i = 0; i < 8; ++i) {
        const int n = nbase + ty * 8 + i;
        const float4 o0 = make_float4(acc[i][0]-offv[0], acc[i][1]-offv[1],
                                      acc[i][2]-offv[2], acc[i][3]-offv[3]);
        const float4 o1 = make_float4(acc[i][4]-offv[4], acc[i][5]-offv[5],
                                      acc[i][6]-offv[6], acc[i][7]-offv[7]);
        *(float4*)(&out[(size_t)n * 128 + tx * 8])     = o0;
        *(float4*)(&out[(size_t)n * 128 + tx * 8 + 4]) = o1;
    }
}

// ---------------------------------------------------------------------------
extern "C" void kernel_launch(void* const* d_in, const int* in_sizes, int n_in,
                              void* d_out, int out_size, void* d_ws, size_t ws_size,
                              hipStream_t stream) {
    float* X   = (float*)d_in[0];
    float* P   = (float*)d_in[1];
    float* A   = (float*)d_in[2];
    float* out = (float*)d_out;
    float* off = (float*)d_ws;            // 128 floats of scratch
    // coef scratch (32896*64 floats = 8.4 MB) lives in d_out (16.8 MB);
    // fully written by jacobi, consumed by recompose, then logits overwrites
    // every element of d_out last.
    float* coefs = (float*)d_out;

    hipLaunchKernelGGL(symmetrize_kernel, dim3((N_P * MAT) / 256), dim3(256), 0, stream, A);
    hipLaunchKernelGGL(jacobi_kernel,     dim3((N_X + N_P) / 4),   dim3(256), 0, stream, X, P, coefs);
    hipLaunchKernelGGL(recompose_kernel,  dim3(N_X + N_P),         dim3(256), 0, stream, X, P, coefs);
    hipLaunchKernelGGL(off_kernel,        dim3(N_P),               dim3(64),  0, stream, P, A, off);
    hipLaunchKernelGGL(logits_kernel,     dim3(N_X / 128),         dim3(256), 0, stream, X, A, off, out);
}

// Round 4
// 4798.593 us; speedup vs baseline: 3.7792x; 3.5604x over previous
//
#include <hip/hip_runtime.h>
#include <math.h>

// Problem constants: N=32768 X-matrices, C=128 classes, n=64.
#define N_X 32768
#define N_P 128
#define ND 64
#define MAT (ND*ND)          // 4096
#define NWAVE 4              // matrices per 256-thread block in eigen_kernel
#define BISECT_ITERS 26

typedef float v2f __attribute__((ext_vector_type(2)));

#if __has_builtin(__builtin_elementwise_fma)
__device__ __forceinline__ v2f vfma(v2f a, v2f b, v2f c) {
    return __builtin_elementwise_fma(a, b, c);
}
#else
__device__ __forceinline__ v2f vfma(v2f a, v2f b, v2f c) {
    return v2f{fmaf(a.x, b.x, c.x), fmaf(a.y, b.y, c.y)};
}
#endif

__device__ __forceinline__ float wsum(float t) {
    #pragma unroll
    for (int m = 1; m < 64; m <<= 1) t += __shfl_xor(t, m);
    return t;
}

__device__ __forceinline__ float frcp(float x) {   // fast approx 1/x (~1 ulp)
    return __builtin_amdgcn_rcpf(x);
}

__device__ __forceinline__ float guard_piv(float p) {
    return (fabsf(p) < 1e-22f) ? -1e-22f : p;
}

// ---------------------------------------------------------------------------
// Kernel 1: symmetrize A in place (tril + tril^T + diag).
// ---------------------------------------------------------------------------
__global__ __launch_bounds__(256) void symmetrize_kernel(float* __restrict__ A) {
    const int idx = blockIdx.x * 256 + threadIdx.x;   // 128*4096 total
    const int r   = (idx >> 6) & 63;
    const int col = idx & 63;
    if (col > r) A[idx] = A[(idx & ~4095) | (col << 6) | r];
}

// ---------------------------------------------------------------------------
// Kernel 2: symmetric eigendecomposition, one wave per matrix, 4 per block.
// Phases: (1) Householder tridiagonalization (lane j owns column j; v,u
// broadcast via LDS), (2) Sturm bisection (lane k -> lambda_k, lane-parallel,
// LDS broadcast reads only), (3) inverse iteration (tiny-pivot Thomas, lane k
// -> eigvec y_k fully in-lane), (4) back-transform y <- Q y via stored
// reflectors, (5) store eigvec columns over M and log(lambda) into coefs.
// ---------------------------------------------------------------------------
__global__ __launch_bounds__(256, 2) void eigen_kernel(float* __restrict__ X,
                                                       float* __restrict__ P,
                                                       float* __restrict__ coefs) {
    __shared__ __align__(16) float Vbuf[NWAVE][64][64];  // rows 0..61: reflectors
    __shared__ __align__(8)  v2f  DEb[NWAVE][64];        // (d_i, e_i)
    const int wid  = threadIdx.x >> 6;
    const int lane = threadIdx.x & 63;
    const int b    = blockIdx.x * NWAVE + wid;
    float* M = (b < N_X) ? (X + (size_t)b * MAT)
                         : (P + (size_t)(b - N_X) * MAT);
    float (*V)[64] = Vbuf[wid];
    v2f* DE        = DEb[wid];
    float* dump    = &V[63][0];   // scratch: column-k dump
    float* ubuf    = &V[62][0];   // scratch: u broadcast

    // ---- load column `lane`; track own diagonal element incrementally ----
    float wcol[64];
    float dg = 0.f;
    #pragma unroll
    for (int i = 0; i < 64; ++i) {
        wcol[i] = M[i * ND + lane];
        if (i == lane) dg = wcol[i];
    }
    float ereg = 0.f;

    // ---- Phase 1: Householder tridiagonalization, steps k = 0..61 ----
    #pragma unroll 1
    for (int k = 0; k < 62; ++k) {
        // lane k dumps its current column to LDS
        if (lane == k) {
            #pragma unroll
            for (int j = 0; j < 16; ++j)
                *(float4*)(&dump[4 * j]) =
                    make_float4(wcol[4*j], wcol[4*j+1], wcol[4*j+2], wcol[4*j+3]);
        }
        __syncthreads();

        const float xj = dump[lane];          // stride-1, conflict-free
        const float x0 = dump[k + 1];         // broadcast
        const float nx2 = wsum((lane > k) ? xj * xj : 0.f);
        const float normx = sqrtf(nx2);
        const float alpha = -copysignf(normx, x0);
        const float vn2   = 2.f * (nx2 - alpha * x0);
        const bool  ok    = (nx2 > 1e-40f);
        const float rvn   = ok ? rsqrtf(vn2) : 0.f;
        float vj = 0.f;
        if (lane == k + 1)      vj = (x0 - alpha) * rvn;
        else if (lane > k)      vj = xj * rvn;
        V[k][lane] = vj;                       // archive reflector (stride-1)
        if (lane == k) ereg = alpha;           // e_k
        __syncthreads();

        // read v into registers (broadcast b128 reads)
        v2f vv[32];
        {
            const float4* vp = (const float4*)(&V[k][0]);
            #pragma unroll
            for (int j = 0; j < 16; ++j) {
                const float4 q = vp[j];
                vv[2*j]   = v2f{q.x, q.y};
                vv[2*j+1] = v2f{q.z, q.w};
            }
        }
        // w_j = 2 * (col_j . v)   (local dot)
        v2f acc = {0.f, 0.f};
        #pragma unroll
        for (int j = 0; j < 32; ++j)
            acc = vfma(v2f{wcol[2*j], wcol[2*j+1]}, vv[j], acc);
        const float wj = 2.f * (acc.x + acc.y);
        const float K  = wsum(vj * wj);
        const float uj = wj - K * vj;
        ubuf[lane] = uj;
        __syncthreads();

        // read u, rank-2 update: col_j -= v*u_j + u*v_j
        {
            const float4* up = (const float4*)(&ubuf[0]);
            const v2f vjv = {vj, vj}, ujv = {uj, uj};
            #pragma unroll
            for (int j = 0; j < 16; ++j) {
                const float4 q = up[j];
                v2f u0 = {q.x, q.y}, u1 = {q.z, q.w};
                v2f w0 = {wcol[4*j],   wcol[4*j+1]};
                v2f w1 = {wcol[4*j+2], wcol[4*j+3]};
                w0 = vfma(-vv[2*j],   ujv, vfma(-u0, vjv, w0));
                w1 = vfma(-vv[2*j+1], ujv, vfma(-u1, vjv, w1));
                wcol[4*j]   = w0.x; wcol[4*j+1] = w0.y;
                wcol[4*j+2] = w1.x; wcol[4*j+3] = w1.y;
            }
        }
        dg -= 2.f * uj * vj;
    }

    if (lane == 62) ereg = wcol[63];          // e_62 = A[63][62] (frozen)
    DE[lane] = v2f{dg, ereg};                 // (d_lane, e_lane)
    __syncthreads();

    // ---- Phase 2: Gershgorin bounds + Sturm bisection (lane k -> lam_k) ----
    float glo = 1e30f, ghi = -1e30f;
    {
        float eprev = 0.f;
        #pragma unroll
        for (int i = 0; i < 64; ++i) {
            const v2f t = DE[i];
            const float e = (i < 63) ? fabsf(t.y) : 0.f;
            const float r = e + eprev;
            glo = fminf(glo, t.x - r);
            ghi = fmaxf(ghi, t.x + r);
            eprev = e;
        }
    }
    float lo = glo, hi = ghi;
    #pragma unroll 1
    for (int it = 0; it < BISECT_ITERS; ++it) {
        const float mid = 0.5f * (lo + hi);
        int cnt = 0;
        float p = 1.f, eprev = 0.f;
        #pragma unroll
        for (int i = 0; i < 64; ++i) {
            const v2f t = DE[i];
            const float num = eprev * eprev;
            p = (t.x - mid) - num * frcp(p);
            p = guard_piv(p);
            cnt += (p < 0.f) ? 1 : 0;
            eprev = t.y;
        }
        if (cnt <= lane) lo = mid; else hi = mid;
    }
    const float lam = 0.5f * (lo + hi);

    // ---- Phase 3: inverse iteration, tiny-pivot Thomas, 2 solves ----
    float rden[64], y[64];
    {
        // factor (reused across solves) + solve 1 with pseudo-random rhs
        float eprev;
        {
            const v2f t0 = DE[0];
            rden[0] = frcp(guard_piv(t0.x - lam));
            eprev = t0.y;
            y[0] = 0.7548f;
        }
        #pragma unroll
        for (int i = 1; i < 64; ++i) {
            const v2f ti = DE[i];
            const float m = eprev * rden[i-1];
            rden[i] = frcp(guard_piv((ti.x - lam) - m * eprev));
            const float bi = (float)(((unsigned)(i * 2654435761u)
                               ^ (unsigned)((lane + 1) * 40503u)) & 0xFFFFu)
                               * 3.0517578e-05f - 0.5f;
            y[i] = bi - m * y[i-1];
            eprev = ti.y;
        }
        y[63] *= rden[63];
        #pragma unroll
        for (int i = 62; i >= 0; --i)
            y[i] = (y[i] - DE[i].y * y[i+1]) * rden[i];

        // normalize, then solve 2 in place
        float n2 = 0.f;
        #pragma unroll
        for (int i = 0; i < 64; ++i) n2 = fmaf(y[i], y[i], n2);
        const float rn = rsqrtf(fmaxf(n2, 1e-30f));
        y[0] *= rn;
        eprev = DE[0].y;
        #pragma unroll
        for (int i = 1; i < 64; ++i) {
            const float m = eprev * rden[i-1];
            y[i] = y[i] * rn - m * y[i-1];
            eprev = DE[i].y;
        }
        y[63] *= rden[63];
        #pragma unroll
        for (int i = 62; i >= 0; --i)
            y[i] = (y[i] - DE[i].y * y[i+1]) * rden[i];
        n2 = 0.f;
        #pragma unroll
        for (int i = 0; i < 64; ++i) n2 = fmaf(y[i], y[i], n2);
        const float rn2 = rsqrtf(fmaxf(n2, 1e-30f));
        #pragma unroll
        for (int i = 0; i < 64; ++i) y[i] *= rn2;
    }

    // ---- Phase 3b: Gram-Schmidt vs lower neighbor when lambdas nearly equal
    {
        const float lamprev = __shfl(lam, lane - 1);
        const bool doGS = (lane > 0) && ((lam - lamprev) < 1e-3f * fabsf(lam));
        float yp[64];
        #pragma unroll
        for (int i = 0; i < 64; ++i) yp[i] = __shfl(y[i], lane - 1);
        float dot = 0.f;
        #pragma unroll
        for (int i = 0; i < 64; ++i) dot = fmaf(y[i], yp[i], dot);
        const float s = doGS ? dot : 0.f;
        float n2 = 0.f;
        #pragma unroll
        for (int i = 0; i < 64; ++i) {
            y[i] = fmaf(-s, yp[i], y[i]);
            n2 = fmaf(y[i], y[i], n2);
        }
        const float rn = rsqrtf(fmaxf(n2, 1e-30f));
        #pragma unroll
        for (int i = 0; i < 64; ++i) y[i] *= rn;
    }

    // ---- Phase 4: back-transform y <- Q y = H_0(...(H_61 y)) ----
    #pragma unroll 1
    for (int k = 61; k >= 0; --k) {
        v2f vv[32];
        const float4* vp = (const float4*)(&V[k][0]);
        #pragma unroll
        for (int j = 0; j < 16; ++j) {
            const float4 q = vp[j];
            vv[2*j]   = v2f{q.x, q.y};
            vv[2*j+1] = v2f{q.z, q.w};
        }
        v2f acc = {0.f, 0.f};
        #pragma unroll
        for (int j = 0; j < 32; ++j)
            acc = vfma(v2f{y[2*j], y[2*j+1]}, vv[j], acc);
        const float s2 = 2.f * (acc.x + acc.y);
        #pragma unroll
        for (int j = 0; j < 32; ++j) {
            y[2*j]   = fmaf(-s2, vv[j].x, y[2*j]);
            y[2*j+1] = fmaf(-s2, vv[j].y, y[2*j+1]);
        }
    }

    // ---- Phase 5: store eigvec column + log(lambda) ----
    #pragma unroll
    for (int i = 0; i < 64; ++i) M[i * ND + lane] = y[i];
    coefs[(size_t)b * ND + lane] = logf(fmaxf(lam, 1e-12f));
}

// ---------------------------------------------------------------------------
// Kernel 3: recompose logm[i][j] = sum_k coef_k * W[i][k] * W[j][k].
// One matrix per 256-thread block, in place over W.
// ---------------------------------------------------------------------------
__global__ __launch_bounds__(256, 4) void recompose_kernel(float* __restrict__ X,
                                                           float* __restrict__ P,
                                                           const float* __restrict__ coefs) {
    __shared__ __align__(16) float WR[ND][68];   // WR[k][i] = W[i][k]
    __shared__ float Cf[ND];
    const int b = blockIdx.x;
    float* M = (b < N_X) ? (X + (size_t)b * MAT)
                         : (P + (size_t)(b - N_X) * MAT);
    const int tid = threadIdx.x;

    { // load + transpose: thread -> row r, 16-col segment q
        const int r = tid >> 2, q = (tid & 3) * 16;
        const float4 v0 = *(const float4*)(&M[r * ND + q + 0]);
        const float4 v1 = *(const float4*)(&M[r * ND + q + 4]);
        const float4 v2 = *(const float4*)(&M[r * ND + q + 8]);
        const float4 v3 = *(const float4*)(&M[r * ND + q + 12]);
        WR[q+ 0][r]=v0.x; WR[q+ 1][r]=v0.y; WR[q+ 2][r]=v0.z; WR[q+ 3][r]=v0.w;
        WR[q+ 4][r]=v1.x; WR[q+ 5][r]=v1.y; WR[q+ 6][r]=v1.z; WR[q+ 7][r]=v1.w;
        WR[q+ 8][r]=v2.x; WR[q+ 9][r]=v2.y; WR[q+10][r]=v2.z; WR[q+11][r]=v2.w;
        WR[q+12][r]=v3.x; WR[q+13][r]=v3.y; WR[q+14][r]=v3.z; WR[q+15][r]=v3.w;
    }
    if (tid < ND) Cf[tid] = coefs[(size_t)b * ND + tid];
    __syncthreads();

    const int tx = tid & 15, ty = tid >> 4;   // 4x4 output block per thread

    v2f a00={0,0},a01={0,0},a10={0,0},a11={0,0},
        a20={0,0},a21={0,0},a30={0,0},a31={0,0};

    #pragma unroll 4
    for (int k = 0; k < ND; ++k) {
        const v2f* row = (const v2f*)(&WR[k][0]);
        const float sk = Cf[k];
        const v2f skv = {sk, sk};
        const v2f aA = row[ty*2], aB = row[ty*2 + 1];
        const v2f b0 = row[tx*2] * skv, b1 = row[tx*2 + 1] * skv;
        const v2f ax0 = {aA.x, aA.x}, ax1 = {aA.y, aA.y};
        const v2f ax2 = {aB.x, aB.x}, ax3 = {aB.y, aB.y};
        a00 = vfma(ax0, b0, a00);  a01 = vfma(ax0, b1, a01);
        a10 = vfma(ax1, b0, a10);  a11 = vfma(ax1, b1, a11);
        a20 = vfma(ax2, b0, a20);  a21 = vfma(ax2, b1, a21);
        a30 = vfma(ax3, b0, a30);  a31 = vfma(ax3, b1, a31);
    }

    const int i0 = ty * 4, j0 = tx * 4;
    *(float4*)(&M[(size_t)(i0+0)*ND + j0]) = make_float4(a00.x,a00.y,a01.x,a01.y);
    *(float4*)(&M[(size_t)(i0+1)*ND + j0]) = make_float4(a10.x,a10.y,a11.x,a11.y);
    *(float4*)(&M[(size_t)(i0+2)*ND + j0]) = make_float4(a20.x,a20.y,a21.x,a21.y);
    *(float4*)(&M[(size_t)(i0+3)*ND + j0]) = make_float4(a30.x,a30.y,a31.x,a31.y);
}

// ---------------------------------------------------------------------------
// Kernel 4: off[c] = <logm(P_c), Asym_c>   (one wave per class)
// ---------------------------------------------------------------------------
__global__ __launch_bounds__(64) void off_kernel(const float* __restrict__ LP,
                                                 const float* __restrict__ AS,
                                                 float* __restrict__ off) {
    const int c = blockIdx.x, lane = threadIdx.x;
    const float* lp = LP + (size_t)c * MAT;
    const float* as = AS + (size_t)c * MAT;
    float t = 0.f;
    #pragma unroll 8
    for (int i = 0; i < ND; ++i)
        t = fmaf(lp[i * ND + lane], as[i * ND + lane], t);
    #pragma unroll
    for (int m = 32; m >= 1; m >>= 1) t += __shfl_xor(t, m);
    if (lane == 0) off[c] = t;
}

// ---------------------------------------------------------------------------
// Kernel 5: logits GEMM  out[n,c] = sum_k LX[n,k]*AS[c,k] - off[c]
// ---------------------------------------------------------------------------
__global__ __launch_bounds__(256) void logits_kernel(const float* __restrict__ LX,
                                                     const float* __restrict__ AS,
                                                     const float* __restrict__ off,
                                                     float* __restrict__ out) {
    __shared__ __align__(16) float LXs[32][132];
    __shared__ __align__(16) float ASs[32][132];
    const int tid = threadIdx.x;
    const int tx = tid & 15, ty = tid >> 4;
    const int nbase = blockIdx.x * 128;

    float offv[8];
    #pragma unroll
    for (int j = 0; j < 8; ++j) offv[j] = off[tx * 8 + j];

    float acc[8][8];
    #pragma unroll
    for (int i = 0; i < 8; ++i)
        #pragma unroll
        for (int j = 0; j < 8; ++j) acc[i][j] = 0.f;

    #pragma unroll 1
    for (int kc = 0; kc < MAT; kc += 32) {
        #pragma unroll
        for (int u = 0; u < 4; ++u) {
            const int f  = u * 256 + tid;
            const int r  = f >> 3;
            const int c4 = (f & 7) * 4;
            const float4 v = *(const float4*)(&LX[(size_t)(nbase + r) * MAT + kc + c4]);
            LXs[c4+0][r] = v.x; LXs[c4+1][r] = v.y; LXs[c4+2][r] = v.z; LXs[c4+3][r] = v.w;
            const float4 g = *(const float4*)(&AS[(size_t)r * MAT + kc + c4]);
            ASs[c4+0][r] = g.x; ASs[c4+1][r] = g.y; ASs[c4+2][r] = g.z; ASs[c4+3][r] = g.w;
        }
        __syncthreads();
        #pragma unroll 4
        for (int kk = 0; kk < 32; ++kk) {
            const float4 a0 = *(const float4*)(&LXs[kk][ty * 8]);
            const float4 a1 = *(const float4*)(&LXs[kk][ty * 8 + 4]);
            const float4 b0 = *(const float4*)(&ASs[kk][tx * 8]);
            const float4 b1 = *(const float4*)(&ASs[kk][tx * 8 + 4]);
            const float av[8] = {a0.x,a0.y,a0.z,a0.w,a1.x,a1.y,a1.z,a1.w};
            const float bv[8] = {b0.x,b0.y,b0.z,b0.w,b1.x,b1.y,b1.z,b1.w};
            #pragma unroll
            for (int i = 0; i < 8; ++i)
                #pragma unroll
                for (int j = 0; j < 8; ++j)
                    acc[i][j] = fmaf(av[i], bv[j], acc[i][j]);
        }
        __syncthreads();
    }

    #pragma unroll
    for (int i = 0; i < 8; ++i) {
        const int n = nbase + ty * 8 + i;
        const float4 o0 = make_float4(acc[i][0]-offv[0], acc[i][1]-offv[1],
                                      acc[i][2]-offv[2], acc[i][3]-offv[3]);
        const float4 o1 = make_float4(acc[i][4]-offv[4], acc[i][5]-offv[5],
                                      acc[i][6]-offv[6], acc[i][7]-offv[7]);
        *(float4*)(&out[(size_t)n * 128 + tx * 8])     = o0;
        *(float4*)(&out[(size_t)n * 128 + tx * 8 + 4]) = o1;
    }
}

// ---------------------------------------------------------------------------
extern "C" void kernel_launch(void* const* d_in, const int* in_sizes, int n_in,
                              void* d_out, int out_size, void* d_ws, size_t ws_size,
                              hipStream_t stream) {
    float* X   = (float*)d_in[0];
    float* P   = (float*)d_in[1];
    float* A   = (float*)d_in[2];
    float* out = (float*)d_out;
    float* off = (float*)d_ws;            // 128 floats of scratch
    // coef scratch (32896*64 floats = 8.4 MB) lives in d_out (16.8 MB):
    // written by eigen, consumed by recompose, then logits overwrites all of
    // d_out last.
    float* coefs = (float*)d_out;

    hipLaunchKernelGGL(symmetrize_kernel, dim3((N_P * MAT) / 256),     dim3(256), 0, stream, A);
    hipLaunchKernelGGL(eigen_kernel,      dim3((N_X + N_P) / NWAVE),   dim3(256), 0, stream, X, P, coefs);
    hipLaunchKernelGGL(recompose_kernel,  dim3(N_X + N_P),             dim3(256), 0, stream, X, P, coefs);
    hipLaunchKernelGGL(off_kernel,        dim3(N_P),                   dim3(64),  0, stream, P, A, off);
    hipLaunchKernelGGL(logits_kernel,     dim3(N_X / 128),             dim3(256), 0, stream, X, A, off, out);
}